// Round 7
// baseline (88.453 us; speedup 1.0000x reference)
//
#include <hip/hip_runtime.h>

// DGCLoss: 1 - mean NDCG. N=384 rows, D=256 feats, M=383 off-diag cols.
//
// Round 7: LDS-free hot loop. R4-R6 evidence: body ~33us at ~91 cyc/wave-term
// vs ~38 issue -> ~55% stall, suspected ds_read+lgkmcnt convoy (srow[c] was an
// LDS broadcast each term). Now: wave loads 64 srow values into a register
// chunk (coalesced, lane L = srow[cbase+L]); inner loop pulls s_c via
// v_readlane (VALU, SGPR result, no memory op, no waitcnt). Same math exactly.
//   dgc_normT : 24 blocks: norms -> XT + XN; out=1.
//   dgc_gram  : 96 blocks x 4 rows: S = scaled gram.
//   dgc_body  : block (n,ih): 192 i's x 2 c-halves, register/readlane sigmoid
//               loop, idcg histogram, relaxed atomicAdd(out, -(dcg/idcg)/N).

#define NN 384
#define DD 256
#define MM 383
// exp(-d*1000) == exp2(s_i - s_j) with s = ((cos+1)*0.5) * 1000*log2(e)
#define HSCALE 721.3475204444817f   // 0.5 * 1000 * log2(e)

__global__ __launch_bounds__(256) void dgc_normT(const float* __restrict__ x,
                                                 float* __restrict__ XT,
                                                 float* __restrict__ XN,
                                                 float* __restrict__ out) {
    __shared__ float xs[16][260];   // +4 pad: conflict-free
    __shared__ float invn[16];

    const int t  = threadIdx.x;
    const int r0 = blockIdx.x * 16;

    if (blockIdx.x == 0 && t == 0) out[0] = 1.0f;

    #pragma unroll
    for (int i = 0; i < 4; ++i) {
        int f = t + i * 256;            // float4 unit 0..1023
        int r = f >> 6, c4 = f & 63;
        float4 v = ((const float4*)(x + (size_t)(r0 + r) * DD))[c4];
        xs[r][c4 * 4 + 0] = v.x; xs[r][c4 * 4 + 1] = v.y;
        xs[r][c4 * 4 + 2] = v.z; xs[r][c4 * 4 + 3] = v.w;
    }
    __syncthreads();

    {   // row norms: 16 threads per row
        const int r = t >> 4, sub = t & 15;
        float s = 0.0f;
        #pragma unroll
        for (int m = 0; m < 16; ++m) {
            float v = xs[r][sub * 16 + m];
            s = fmaf(v, v, s);
        }
        #pragma unroll
        for (int off = 8; off > 0; off >>= 1) s += __shfl_xor(s, off, 64);
        if (sub == 0) invn[r] = __builtin_amdgcn_rsqf(fmaxf(s, 1e-16f));
    }
    __syncthreads();

    {   // normalized transpose XT[k][r0+r]
        const int r  = t & 15;
        const int kk = t >> 4;
        const float inv = invn[r];
        #pragma unroll
        for (int i = 0; i < 16; ++i) {
            int k = i * 16 + kk;
            XT[(size_t)k * NN + r0 + r] = xs[r][k] * inv;
        }
    }
    {   // normalized row-major XN (coalesced)
        #pragma unroll
        for (int i = 0; i < 4; ++i) {
            int f = t + i * 256;
            int r = f >> 6, c4 = f & 63;
            const float inv = invn[r];
            float4 v;
            v.x = xs[r][c4 * 4 + 0] * inv; v.y = xs[r][c4 * 4 + 1] * inv;
            v.z = xs[r][c4 * 4 + 2] * inv; v.w = xs[r][c4 * 4 + 3] * inv;
            ((float4*)(XN + (size_t)(r0 + r) * DD))[c4] = v;
        }
    }
}

__global__ __launch_bounds__(384) void dgc_gram(const float* __restrict__ XN,
                                                const float* __restrict__ XT,
                                                float* __restrict__ S) {
    __shared__ __align__(16) float xs4[DD][4];   // [k][r], b128 broadcast reads

    const int t  = threadIdx.x;
    const int n0 = blockIdx.x * 4;

    if (t < 256) {
        int r = t >> 6, c4 = t & 63;
        float4 v = ((const float4*)(XN + (size_t)(n0 + r) * DD))[c4];
        xs4[c4 * 4 + 0][r] = v.x; xs4[c4 * 4 + 1][r] = v.y;
        xs4[c4 * 4 + 2][r] = v.z; xs4[c4 * 4 + 3][r] = v.w;
    }
    __syncthreads();

    const int j = t;                               // 0..383, lane-consecutive
    float a0 = 0.f, a1 = 0.f, a2 = 0.f, a3 = 0.f;
    #pragma unroll 8
    for (int k = 0; k < DD; ++k) {
        float b = XT[(size_t)k * NN + j];          // coalesced
        float4 s = *(const float4*)xs4[k];         // ds_read_b128 broadcast
        a0 = fmaf(s.x, b, a0); a1 = fmaf(s.y, b, a1);
        a2 = fmaf(s.z, b, a2); a3 = fmaf(s.w, b, a3);
    }
    S[(size_t)(n0 + 0) * NN + j] = fmaf(a0, HSCALE, HSCALE);
    S[(size_t)(n0 + 1) * NN + j] = fmaf(a1, HSCALE, HSCALE);
    S[(size_t)(n0 + 2) * NN + j] = fmaf(a2, HSCALE, HSCALE);
    S[(size_t)(n0 + 3) * NN + j] = fmaf(a3, HSCALE, HSCALE);
}

__device__ __forceinline__ float rl(float v, int m) {
    return __int_as_float(__builtin_amdgcn_readlane(__float_as_int(v), m));
}

__global__ __launch_bounds__(384) void dgc_body(const float* __restrict__ S,
                                                const int* __restrict__ gt,
                                                float* __restrict__ out) {
    __shared__ float pbody[2][192];
    __shared__ float redd[3], redi[6];
    __shared__ int   hist[6], cum[6];

    const int n    = blockIdx.x >> 1;
    const int ih   = blockIdx.x & 1;
    const int t    = threadIdx.x;
    const int lane = t & 63;
    const int wave = t >> 6;

    const float* Srow = S + (size_t)n * NN;

    if (t < 6) hist[t] = 0;

    // ---- sigmoid sums: i = ih*192 + t%192, c-half = t/192 (waves 0-2/3-5) ----
    const int   il    = t % 192;
    const int   ch    = t / 192;
    const int   i     = ih * 192 + il;
    const bool  valid = (i < MM);
    const int   col   = valid ? (i + (i >= n ? 1 : 0)) : 0;
    const float ri    = Srow[col];      // near-coalesced per-lane gather
    const float sn    = Srow[n];        // uniform scalar load

    float p0 = 0.0f, p1 = 0.0f;
    const int cbase = ch * 192;
    #pragma unroll
    for (int chunk = 0; chunk < 3; ++chunk) {
        // lane L holds srow[cbase + chunk*64 + L]; coalesced 256B/wave load
        const float cv = Srow[cbase + chunk * 64 + lane];
        #pragma unroll
        for (int m = 0; m < 64; m += 2) {
            // s_c via v_readlane -> SGPR: no LDS, no waitcnt in the hot loop
            float s0 = rl(cv, m);
            float s1 = rl(cv, m + 1);
            p0 += __builtin_amdgcn_rcpf(1.0f + __builtin_amdgcn_exp2f(ri - s0));
            p1 += __builtin_amdgcn_rcpf(1.0f + __builtin_amdgcn_exp2f(ri - s1));
        }
    }
    float partial = p0 + p1;
    if (n >= cbase && n < cbase + 192) {   // remove diagonal col (uniform branch)
        partial -= __builtin_amdgcn_rcpf(1.0f + __builtin_amdgcn_exp2f(ri - sn));
    }
    pbody[ch][il] = partial;
    __syncthreads();

    // ---- full-row histogram for idcg (same in both half-blocks) ----
    if (t < MM) {
        int gd = gt[t + (t >= n ? 1 : 0)] - gt[n];
        atomicAdd(&hist[gd < 0 ? -gd : gd], 1);
    }
    __syncthreads();
    if (t == 0) {
        int s = 0;
        for (int g = 0; g < 6; ++g) { s += hist[g]; cum[g] = s; }
    }
    __syncthreads();

    // ---- idcg over all 383 sorted positions ----
    float idcg_i = 0.0f;
    if (t < MM) {
        int p = t, g = 0;
        while (p >= cum[g]) ++g;                 // cum[5]==383 > p always
        idcg_i = (float)((1 << (10 - g)) - 1) / __log2f((float)(p + 2));
    }

    // ---- dcg for this block's 192 i's (ch==0 threads finalize) ----
    float dcg_i = 0.0f;
    if (ch == 0 && valid) {
        // self term (c==col) was exactly 0.5: ind = 1 + (sum - 0.5)
        float ind = pbody[0][il] + pbody[1][il] + 0.5f;
        int gd = gt[col] - gt[n];
        int gi = gd < 0 ? -gd : gd;
        dcg_i = (float)((1 << (10 - gi)) - 1) / __log2f(ind + 1.0f);
    }

    #pragma unroll
    for (int off = 32; off > 0; off >>= 1) {
        dcg_i  += __shfl_down(dcg_i,  off, 64);
        idcg_i += __shfl_down(idcg_i, off, 64);
    }
    if (lane == 0) {
        redi[wave] = idcg_i;
        if (wave < 3) redd[wave] = dcg_i;
    }
    __syncthreads();
    if (t == 0) {
        float d  = redd[0] + redd[1] + redd[2];
        float id = redi[0] + redi[1] + redi[2] + redi[3] + redi[4] + redi[5];
        atomicAdd(out, -(d / id) * (1.0f / (float)NN));   // relaxed scope
    }
}

extern "C" void kernel_launch(void* const* d_in, const int* in_sizes, int n_in,
                              void* d_out, int out_size, void* d_ws, size_t ws_size,
                              hipStream_t stream) {
    const float* ranking = (const float*)d_in[0];
    const int*   gt      = (const int*)d_in[1];
    float*       out     = (float*)d_out;

    float* XT = (float*)d_ws;                  // 256*384
    float* XN = XT + (size_t)DD * NN;          // 384*256
    float* S  = XN + (size_t)NN * DD;          // 384*384

    dgc_normT<<<24, 256, 0, stream>>>(ranking, XT, XN, out);
    dgc_gram<<<96, 384, 0, stream>>>(XN, XT, S);
    dgc_body<<<768, 384, 0, stream>>>(S, gt, out);
}

// Round 8
// 82.883 us; speedup vs baseline: 1.0672x; 1.0672x over previous
//
#include <hip/hip_runtime.h>

// DGCLoss: 1 - mean NDCG. N=384 rows, D=256 feats, M=383 off-diag cols.
//
// Round 8: term-count reduction. R5-R7: body ~30us invariant to hot-loop
// implementation -> cost scales with sigmoid TERM COUNT (~90cyc/wave-term,
// trans-unit suspected). K=0.001 => sigmoid is a near-step: term differs
// from {0,1} by >2^-16 only when |ri-sc|<16 s-units (and fp32 ref is EXACTLY
// 1.0 for delta>=24). Per row: 256-bucket counting sort (LDS atomics + one
// wave scan + scatter), hard count from prefix bounds (free), exact exp2/rcp
// only over the ~100-position soft window. Tail error ~5e-5 in ind, ~1e-5
// in the final loss (threshold 3.6e-3).
//   dgc_normT : unchanged. dgc_gram : unchanged.
//   dgc_body  : block n = sorted-window NDCG row.

#define NN 384
#define DD 256
#define MM 383
// exp(-d*1000) == exp2(s_i - s_j) with s = ((cos+1)*0.5) * 1000*log2(e)
#define HSCALE 721.3475204444817f   // 0.5 * 1000 * log2(e)
#define NBUCK  256
#define BSCALE 0.1767955801104972f  // 256 / 1448  (values in [0, 1442.7])
#define WWIN   16.0f                // soft-window half-width in s-units

__global__ __launch_bounds__(256) void dgc_normT(const float* __restrict__ x,
                                                 float* __restrict__ XT,
                                                 float* __restrict__ XN,
                                                 float* __restrict__ out) {
    __shared__ float xs[16][260];   // +4 pad: conflict-free
    __shared__ float invn[16];

    const int t  = threadIdx.x;
    const int r0 = blockIdx.x * 16;

    if (blockIdx.x == 0 && t == 0) out[0] = 1.0f;

    #pragma unroll
    for (int i = 0; i < 4; ++i) {
        int f = t + i * 256;            // float4 unit 0..1023
        int r = f >> 6, c4 = f & 63;
        float4 v = ((const float4*)(x + (size_t)(r0 + r) * DD))[c4];
        xs[r][c4 * 4 + 0] = v.x; xs[r][c4 * 4 + 1] = v.y;
        xs[r][c4 * 4 + 2] = v.z; xs[r][c4 * 4 + 3] = v.w;
    }
    __syncthreads();

    {   // row norms: 16 threads per row
        const int r = t >> 4, sub = t & 15;
        float s = 0.0f;
        #pragma unroll
        for (int m = 0; m < 16; ++m) {
            float v = xs[r][sub * 16 + m];
            s = fmaf(v, v, s);
        }
        #pragma unroll
        for (int off = 8; off > 0; off >>= 1) s += __shfl_xor(s, off, 64);
        if (sub == 0) invn[r] = __builtin_amdgcn_rsqf(fmaxf(s, 1e-16f));
    }
    __syncthreads();

    {   // normalized transpose XT[k][r0+r]
        const int r  = t & 15;
        const int kk = t >> 4;
        const float inv = invn[r];
        #pragma unroll
        for (int i = 0; i < 16; ++i) {
            int k = i * 16 + kk;
            XT[(size_t)k * NN + r0 + r] = xs[r][k] * inv;
        }
    }
    {   // normalized row-major XN (coalesced)
        #pragma unroll
        for (int i = 0; i < 4; ++i) {
            int f = t + i * 256;
            int r = f >> 6, c4 = f & 63;
            const float inv = invn[r];
            float4 v;
            v.x = xs[r][c4 * 4 + 0] * inv; v.y = xs[r][c4 * 4 + 1] * inv;
            v.z = xs[r][c4 * 4 + 2] * inv; v.w = xs[r][c4 * 4 + 3] * inv;
            ((float4*)(XN + (size_t)(r0 + r) * DD))[c4] = v;
        }
    }
}

__global__ __launch_bounds__(384) void dgc_gram(const float* __restrict__ XN,
                                                const float* __restrict__ XT,
                                                float* __restrict__ S) {
    __shared__ __align__(16) float xs4[DD][4];   // [k][r], b128 broadcast reads

    const int t  = threadIdx.x;
    const int n0 = blockIdx.x * 4;

    if (t < 256) {
        int r = t >> 6, c4 = t & 63;
        float4 v = ((const float4*)(XN + (size_t)(n0 + r) * DD))[c4];
        xs4[c4 * 4 + 0][r] = v.x; xs4[c4 * 4 + 1][r] = v.y;
        xs4[c4 * 4 + 2][r] = v.z; xs4[c4 * 4 + 3][r] = v.w;
    }
    __syncthreads();

    const int j = t;                               // 0..383, lane-consecutive
    float a0 = 0.f, a1 = 0.f, a2 = 0.f, a3 = 0.f;
    #pragma unroll 8
    for (int k = 0; k < DD; ++k) {
        float b = XT[(size_t)k * NN + j];          // coalesced
        float4 s = *(const float4*)xs4[k];         // ds_read_b128 broadcast
        a0 = fmaf(s.x, b, a0); a1 = fmaf(s.y, b, a1);
        a2 = fmaf(s.z, b, a2); a3 = fmaf(s.w, b, a3);
    }
    S[(size_t)(n0 + 0) * NN + j] = fmaf(a0, HSCALE, HSCALE);
    S[(size_t)(n0 + 1) * NN + j] = fmaf(a1, HSCALE, HSCALE);
    S[(size_t)(n0 + 2) * NN + j] = fmaf(a2, HSCALE, HSCALE);
    S[(size_t)(n0 + 3) * NN + j] = fmaf(a3, HSCALE, HSCALE);
}

__global__ __launch_bounds__(384) void dgc_body(const float* __restrict__ S,
                                                const int* __restrict__ gt,
                                                float* __restrict__ out) {
    __shared__ float vsort[NN];
    __shared__ int   sidx[NN];
    __shared__ int   hist[NBUCK];
    __shared__ int   pre[NBUCK + 1];
    __shared__ float sn_sh;
    __shared__ float redd[6], redi[6];
    __shared__ int   ghist[6], gcum[6];

    const int n    = blockIdx.x;
    const int t    = threadIdx.x;
    const int lane = t & 63;
    const int wave = t >> 6;

    const float vraw = S[(size_t)n * NN + t];    // coalesced row read
    if (t < NBUCK) hist[t] = 0;
    if (t < 6) ghist[t] = 0;
    if (t == n) sn_sh = vraw;                    // diagonal value
    __syncthreads();

    // ---- counting sort, phase 1: bucket insert (slot = stable offset) ----
    int b = (int)(vraw * BSCALE);
    b = b < 0 ? 0 : (b > NBUCK - 1 ? NBUCK - 1 : b);
    const int slot = atomicAdd(&hist[b], 1);
    __syncthreads();

    // ---- phase 2: wave 0 exclusive-scans hist -> pre[0..256] ----
    if (wave == 0) {
        const int s0 = hist[lane * 4 + 0], s1 = hist[lane * 4 + 1];
        const int s2 = hist[lane * 4 + 2], s3 = hist[lane * 4 + 3];
        const int sum = s0 + s1 + s2 + s3;
        int inc = sum;
        #pragma unroll
        for (int off = 1; off < 64; off <<= 1) {
            int u = __shfl_up(inc, off, 64);
            if (lane >= off) inc += u;
        }
        const int base = inc - sum;
        pre[lane * 4 + 0] = base;
        pre[lane * 4 + 1] = base + s0;
        pre[lane * 4 + 2] = base + s0 + s1;
        pre[lane * 4 + 3] = base + s0 + s1 + s2;
        if (lane == 63) pre[NBUCK] = inc;        // = 384
    }
    __syncthreads();

    // ---- phase 3: scatter into bucket-sorted order ----
    {
        const int pos = pre[b] + slot;
        vsort[pos] = vraw;
        sidx[pos]  = t;
    }
    __syncthreads();

    // ---- phase 4: thread = sorted position t ----
    const float ri    = vsort[t];
    const int   iorig = sidx[t];
    const float sn    = sn_sh;

    int Blo = (int)((ri - WWIN) * BSCALE);
    int Bhi = (int)((ri + WWIN) * BSCALE);
    Blo = Blo < 0 ? 0 : (Blo > NBUCK - 1 ? NBUCK - 1 : Blo);
    Bhi = Bhi < 0 ? 0 : (Bhi > NBUCK - 1 ? NBUCK - 1 : Bhi);
    const int lo = pre[Blo];        // below lo: v < ri-W  -> term ~ 0
    const int hi = pre[Bhi + 1];    // at/above hi: v > ri+W -> term ~ 1 (fp32-exact for d>=24)

    float p0 = 0.0f, p1 = 0.0f;
    int q = lo;
    for (; q + 2 <= hi; q += 2) {
        p0 += __builtin_amdgcn_rcpf(1.0f + __builtin_amdgcn_exp2f(ri - vsort[q]));
        p1 += __builtin_amdgcn_rcpf(1.0f + __builtin_amdgcn_exp2f(ri - vsort[q + 1]));
    }
    if (q < hi)
        p0 += __builtin_amdgcn_rcpf(1.0f + __builtin_amdgcn_exp2f(ri - vsort[q]));
    float sum_all = (float)(NN - hi) + p0 + p1;

    // diagonal (c == n) correction, bucket-consistent with the loop above
    int bn = (int)(sn * BSCALE);
    bn = bn < 0 ? 0 : (bn > NBUCK - 1 ? NBUCK - 1 : bn);
    float cd = 0.0f;
    if (bn > Bhi)       cd = 1.0f;
    else if (bn >= Blo) cd = __builtin_amdgcn_rcpf(1.0f + __builtin_amdgcn_exp2f(ri - sn));
    // self term (q == t, sigma(0)=0.5) always in-window: ind = 1 + sum - 0.5 - cd
    const float ind = 0.5f + sum_all - cd;

    // ---- idcg histogram over gt (original column order, as before) ----
    if (t < MM) {
        const int col = t + (t >= n ? 1 : 0);
        const int gd = gt[col] - gt[n];
        atomicAdd(&ghist[gd < 0 ? -gd : gd], 1);
    }
    __syncthreads();
    if (t == 0) {
        int s = 0;
        for (int g = 0; g < 6; ++g) { s += ghist[g]; gcum[g] = s; }
    }
    __syncthreads();

    float idcg_i = 0.0f;
    if (t < MM) {
        int p = t, g = 0;
        while (p >= gcum[g]) ++g;                // gcum[5]==383 > p always
        idcg_i = (float)((1 << (10 - g)) - 1) / __log2f((float)(p + 2));
    }

    float dcg_i = 0.0f;
    if (iorig != n) {                            // permutation covers all 383 real cols
        const int gd = gt[iorig] - gt[n];
        const int gi = gd < 0 ? -gd : gd;
        dcg_i = (float)((1 << (10 - gi)) - 1) / __log2f(ind + 1.0f);
    }

    #pragma unroll
    for (int off = 32; off > 0; off >>= 1) {
        dcg_i  += __shfl_down(dcg_i,  off, 64);
        idcg_i += __shfl_down(idcg_i, off, 64);
    }
    if (lane == 0) { redd[wave] = dcg_i; redi[wave] = idcg_i; }
    __syncthreads();
    if (t == 0) {
        float d = 0.0f, id = 0.0f;
        for (int w = 0; w < 6; ++w) { d += redd[w]; id += redi[w]; }
        atomicAdd(out, -(d / id) * (1.0f / (float)NN));   // relaxed scope
    }
}

extern "C" void kernel_launch(void* const* d_in, const int* in_sizes, int n_in,
                              void* d_out, int out_size, void* d_ws, size_t ws_size,
                              hipStream_t stream) {
    const float* ranking = (const float*)d_in[0];
    const int*   gt      = (const int*)d_in[1];
    float*       out     = (float*)d_out;

    float* XT = (float*)d_ws;                  // 256*384
    float* XN = XT + (size_t)DD * NN;          // 384*256
    float* S  = XN + (size_t)NN * DD;          // 384*384

    dgc_normT<<<24, 256, 0, stream>>>(ranking, XT, XN, out);
    dgc_gram<<<96, 384, 0, stream>>>(XN, XT, S);
    dgc_body<<<NN, 384, 0, stream>>>(S, gt, out);
}

// Round 9
// 74.519 us; speedup vs baseline: 1.1870x; 1.1122x over previous
//
#include <hip/hip_runtime.h>

// DGCLoss: 1 - mean NDCG. N=384 rows, D=256 feats, M=383 off-diag cols.
//
// Round 9: fuse gram into body + kill same-address LDS atomics.
// R8 falsified the per-term cost model (3.7x fewer sigmoid terms -> -4.7us
// only); an invariant ~20us lives in the split gram/body structure. Now:
//   dgc_normT : 24 blocks: norms -> XT (transposed) + XN (row-major); out=1.
//   dgc_fused : block n (384 thr): S-row computed in-block (coalesced XT
//               stream, no S round-trip), 256-bucket counting sort, sorted
//               soft-window sigmoid (hard tails free), idcg via ballot
//               histogram (no LDS atomic storm), relaxed atomicAdd(out).

#define NN 384
#define DD 256
#define MM 383
// exp(-d*1000) == exp2(s_i - s_j) with s = ((cos+1)*0.5) * 1000*log2(e)
#define HSCALE 721.3475204444817f   // 0.5 * 1000 * log2(e)
#define NBUCK  256
#define BSCALE 0.1767955801104972f  // 256 / 1448  (values in [0, 1442.7])
#define WWIN   16.0f                // soft-window half-width in s-units

__global__ __launch_bounds__(256) void dgc_normT(const float* __restrict__ x,
                                                 float* __restrict__ XT,
                                                 float* __restrict__ XN,
                                                 float* __restrict__ out) {
    __shared__ float xs[16][260];   // +4 pad: conflict-free
    __shared__ float invn[16];

    const int t  = threadIdx.x;
    const int r0 = blockIdx.x * 16;

    if (blockIdx.x == 0 && t == 0) out[0] = 1.0f;

    #pragma unroll
    for (int i = 0; i < 4; ++i) {
        int f = t + i * 256;            // float4 unit 0..1023
        int r = f >> 6, c4 = f & 63;
        float4 v = ((const float4*)(x + (size_t)(r0 + r) * DD))[c4];
        xs[r][c4 * 4 + 0] = v.x; xs[r][c4 * 4 + 1] = v.y;
        xs[r][c4 * 4 + 2] = v.z; xs[r][c4 * 4 + 3] = v.w;
    }
    __syncthreads();

    {   // row norms: 16 threads per row
        const int r = t >> 4, sub = t & 15;
        float s = 0.0f;
        #pragma unroll
        for (int m = 0; m < 16; ++m) {
            float v = xs[r][sub * 16 + m];
            s = fmaf(v, v, s);
        }
        #pragma unroll
        for (int off = 8; off > 0; off >>= 1) s += __shfl_xor(s, off, 64);
        if (sub == 0) invn[r] = __builtin_amdgcn_rsqf(fmaxf(s, 1e-16f));
    }
    __syncthreads();

    {   // normalized transpose XT[k][r0+r]
        const int r  = t & 15;
        const int kk = t >> 4;
        const float inv = invn[r];
        #pragma unroll
        for (int i = 0; i < 16; ++i) {
            int k = i * 16 + kk;
            XT[(size_t)k * NN + r0 + r] = xs[r][k] * inv;
        }
    }
    {   // normalized row-major XN (coalesced)
        #pragma unroll
        for (int i = 0; i < 4; ++i) {
            int f = t + i * 256;
            int r = f >> 6, c4 = f & 63;
            const float inv = invn[r];
            float4 v;
            v.x = xs[r][c4 * 4 + 0] * inv; v.y = xs[r][c4 * 4 + 1] * inv;
            v.z = xs[r][c4 * 4 + 2] * inv; v.w = xs[r][c4 * 4 + 3] * inv;
            ((float4*)(XN + (size_t)(r0 + r) * DD))[c4] = v;
        }
    }
}

__global__ __launch_bounds__(384) void dgc_fused(const float* __restrict__ XT,
                                                 const float* __restrict__ XN,
                                                 const int* __restrict__ gt,
                                                 float* __restrict__ out) {
    __shared__ float xs[DD];          // normalized row n
    __shared__ float srow[NN];        // scaled similarity row (in-block gram)
    __shared__ float vsort[NN];
    __shared__ int   sidx[NN];
    __shared__ int   hist[NBUCK];
    __shared__ int   pre[NBUCK + 1];
    __shared__ int   wcnt[6][6];      // [wave][g] ballot counts
    __shared__ int   gcum[6];
    __shared__ float redd[6], redi[6];

    const int n    = blockIdx.x;
    const int t    = threadIdx.x;
    const int lane = t & 63;
    const int wave = t >> 6;

    if (t < DD / 4) ((float4*)xs)[t] = ((const float4*)(XN + (size_t)n * DD))[t];
    if (t < NBUCK) hist[t] = 0;
    __syncthreads();

    // ---- gram: thread j = t computes S[n][j], coalesced XT column stream ----
    {
        const float* Xc = XT + t;
        float d0 = 0.0f, d1 = 0.0f;
        #pragma unroll 8
        for (int k = 0; k < DD; k += 2) {
            d0 = fmaf(xs[k],     Xc[(size_t)k * NN],       d0);
            d1 = fmaf(xs[k + 1], Xc[(size_t)(k + 1) * NN], d1);
        }
        srow[t] = fmaf(d0 + d1, HSCALE, HSCALE);
    }
    __syncthreads();

    const float vraw = srow[t];
    const float sn   = srow[n];       // LDS broadcast

    // ---- counting sort, phase 1: bucket insert ----
    int b = (int)(vraw * BSCALE);
    b = b < 0 ? 0 : (b > NBUCK - 1 ? NBUCK - 1 : b);
    const int slot = atomicAdd(&hist[b], 1);   // 384 adds over 256 buckets: shallow

    // ---- idcg histogram via ballot (no same-address atomic storm) ----
    const bool validc = (t < MM);
    int gi = 0;
    if (validc) {
        const int gd = gt[t + (t >= n ? 1 : 0)] - gt[n];
        gi = gd < 0 ? -gd : gd;       // 0..5
    }
    #pragma unroll
    for (int g = 0; g < 6; ++g) {
        unsigned long long m = __ballot(validc && (gi == g));
        if (lane == g) wcnt[wave][g] = __popcll(m);
    }
    __syncthreads();

    // ---- phase 2: wave 0 exclusive-scans hist -> pre[0..256]; t==0 gcum ----
    if (wave == 0) {
        const int s0 = hist[lane * 4 + 0], s1 = hist[lane * 4 + 1];
        const int s2 = hist[lane * 4 + 2], s3 = hist[lane * 4 + 3];
        const int sum = s0 + s1 + s2 + s3;
        int inc = sum;
        #pragma unroll
        for (int off = 1; off < 64; off <<= 1) {
            int u = __shfl_up(inc, off, 64);
            if (lane >= off) inc += u;
        }
        const int base = inc - sum;
        pre[lane * 4 + 0] = base;
        pre[lane * 4 + 1] = base + s0;
        pre[lane * 4 + 2] = base + s0 + s1;
        pre[lane * 4 + 3] = base + s0 + s1 + s2;
        if (lane == 63) pre[NBUCK] = inc;        // = 384
    }
    if (t == 0) {
        int s = 0;
        #pragma unroll
        for (int g = 0; g < 6; ++g) {
            s += wcnt[0][g] + wcnt[1][g] + wcnt[2][g]
               + wcnt[3][g] + wcnt[4][g] + wcnt[5][g];
            gcum[g] = s;
        }
    }
    __syncthreads();

    // ---- phase 3: scatter into bucket-sorted order ----
    {
        const int pos = pre[b] + slot;
        vsort[pos] = vraw;
        sidx[pos]  = t;
    }
    __syncthreads();

    // ---- phase 4: thread = sorted position t; soft window only ----
    const float ri    = vsort[t];
    const int   iorig = sidx[t];

    int Blo = (int)((ri - WWIN) * BSCALE);
    int Bhi = (int)((ri + WWIN) * BSCALE);
    Blo = Blo < 0 ? 0 : (Blo > NBUCK - 1 ? NBUCK - 1 : Blo);
    Bhi = Bhi < 0 ? 0 : (Bhi > NBUCK - 1 ? NBUCK - 1 : Bhi);
    const int lo = pre[Blo];        // below: term ~ 0
    const int hi = pre[Bhi + 1];    // at/above: term == 1.0 in fp32 (d >= 24)

    float p0 = 0.0f, p1 = 0.0f;
    int q = lo;
    for (; q + 2 <= hi; q += 2) {
        p0 += __builtin_amdgcn_rcpf(1.0f + __builtin_amdgcn_exp2f(ri - vsort[q]));
        p1 += __builtin_amdgcn_rcpf(1.0f + __builtin_amdgcn_exp2f(ri - vsort[q + 1]));
    }
    if (q < hi)
        p0 += __builtin_amdgcn_rcpf(1.0f + __builtin_amdgcn_exp2f(ri - vsort[q]));
    float sum_all = (float)(NN - hi) + p0 + p1;

    // diagonal (c == n) correction, bucket-consistent with the window
    int bn = (int)(sn * BSCALE);
    bn = bn < 0 ? 0 : (bn > NBUCK - 1 ? NBUCK - 1 : bn);
    float cd = 0.0f;
    if (bn > Bhi)       cd = 1.0f;
    else if (bn >= Blo) cd = __builtin_amdgcn_rcpf(1.0f + __builtin_amdgcn_exp2f(ri - sn));
    // self term (sigma(0)=0.5) always in-window: ind = 1 + sum - 0.5 - cd
    const float ind = 0.5f + sum_all - cd;

    // ---- idcg at sorted-rel position p = t (g from cumulative counts) ----
    float idcg_i = 0.0f;
    if (validc) {
        const int p = t;
        const int g = (p >= gcum[0]) + (p >= gcum[1]) + (p >= gcum[2])
                    + (p >= gcum[3]) + (p >= gcum[4]);   // gcum[5]==383 > p
        idcg_i = (float)((1 << (10 - g)) - 1) / __builtin_amdgcn_logf((float)(p + 2));
    }

    // ---- dcg for this sorted position ----
    float dcg_i = 0.0f;
    if (iorig != n) {               // permutation covers all 383 real cols
        const int gd = gt[iorig] - gt[n];
        const int gg = gd < 0 ? -gd : gd;
        dcg_i = (float)((1 << (10 - gg)) - 1) / __builtin_amdgcn_logf(ind + 1.0f);
    }

    #pragma unroll
    for (int off = 32; off > 0; off >>= 1) {
        dcg_i  += __shfl_down(dcg_i,  off, 64);
        idcg_i += __shfl_down(idcg_i, off, 64);
    }
    if (lane == 0) { redd[wave] = dcg_i; redi[wave] = idcg_i; }
    __syncthreads();
    if (t == 0) {
        float d = 0.0f, id = 0.0f;
        #pragma unroll
        for (int w = 0; w < 6; ++w) { d += redd[w]; id += redi[w]; }
        atomicAdd(out, -(d / id) * (1.0f / (float)NN));   // relaxed scope
    }
}

extern "C" void kernel_launch(void* const* d_in, const int* in_sizes, int n_in,
                              void* d_out, int out_size, void* d_ws, size_t ws_size,
                              hipStream_t stream) {
    const float* ranking = (const float*)d_in[0];
    const int*   gt      = (const int*)d_in[1];
    float*       out     = (float*)d_out;

    float* XT = (float*)d_ws;                  // 256*384
    float* XN = XT + (size_t)DD * NN;          // 384*256

    dgc_normT<<<24, 256, 0, stream>>>(ranking, XT, XN, out);
    dgc_fused<<<NN, 384, 0, stream>>>(XT, XN, gt, out);
}

// Round 10
// 74.100 us; speedup vs baseline: 1.1937x; 1.0057x over previous
//
#include <hip/hip_runtime.h>

// DGCLoss: 1 - mean NDCG. N=384 rows, D=256 feats, M=383 off-diag cols.
//
// Round 10: float4 split-K gram inside the fused kernel. R9 ledger: wall =
// 2 x T_block (384 blocks / 256 CUs), T_block ~8us dominated by the gram's
// 256 scalar global loads (~32 latency windows). Now: thread=(j4,kc) does
// 64 float4 loads (~8 windows), LDS partial reduce. Sort/soft-window/idcg
// unchanged from R9.
//   dgc_normT : 24 blocks: norms -> XT + XN; out=1.
//   dgc_fused : block n: split-K gram -> srow, counting sort, soft-window
//               sigmoid, ballot idcg, relaxed atomicAdd(out).

#define NN 384
#define DD 256
#define MM 383
// exp(-d*1000) == exp2(s_i - s_j) with s = ((cos+1)*0.5) * 1000*log2(e)
#define HSCALE 721.3475204444817f   // 0.5 * 1000 * log2(e)
#define NBUCK  256
#define BSCALE 0.1767955801104972f  // 256 / 1448  (values in [0, 1442.7])
#define WWIN   16.0f                // soft-window half-width in s-units

__global__ __launch_bounds__(256) void dgc_normT(const float* __restrict__ x,
                                                 float* __restrict__ XT,
                                                 float* __restrict__ XN,
                                                 float* __restrict__ out) {
    __shared__ float xs[16][260];   // +4 pad: conflict-free
    __shared__ float invn[16];

    const int t  = threadIdx.x;
    const int r0 = blockIdx.x * 16;

    if (blockIdx.x == 0 && t == 0) out[0] = 1.0f;

    #pragma unroll
    for (int i = 0; i < 4; ++i) {
        int f = t + i * 256;            // float4 unit 0..1023
        int r = f >> 6, c4 = f & 63;
        float4 v = ((const float4*)(x + (size_t)(r0 + r) * DD))[c4];
        xs[r][c4 * 4 + 0] = v.x; xs[r][c4 * 4 + 1] = v.y;
        xs[r][c4 * 4 + 2] = v.z; xs[r][c4 * 4 + 3] = v.w;
    }
    __syncthreads();

    {   // row norms: 16 threads per row
        const int r = t >> 4, sub = t & 15;
        float s = 0.0f;
        #pragma unroll
        for (int m = 0; m < 16; ++m) {
            float v = xs[r][sub * 16 + m];
            s = fmaf(v, v, s);
        }
        #pragma unroll
        for (int off = 8; off > 0; off >>= 1) s += __shfl_xor(s, off, 64);
        if (sub == 0) invn[r] = __builtin_amdgcn_rsqf(fmaxf(s, 1e-16f));
    }
    __syncthreads();

    {   // normalized transpose XT[k][r0+r]
        const int r  = t & 15;
        const int kk = t >> 4;
        const float inv = invn[r];
        #pragma unroll
        for (int i = 0; i < 16; ++i) {
            int k = i * 16 + kk;
            XT[(size_t)k * NN + r0 + r] = xs[r][k] * inv;
        }
    }
    {   // normalized row-major XN (coalesced)
        #pragma unroll
        for (int i = 0; i < 4; ++i) {
            int f = t + i * 256;
            int r = f >> 6, c4 = f & 63;
            const float inv = invn[r];
            float4 v;
            v.x = xs[r][c4 * 4 + 0] * inv; v.y = xs[r][c4 * 4 + 1] * inv;
            v.z = xs[r][c4 * 4 + 2] * inv; v.w = xs[r][c4 * 4 + 3] * inv;
            ((float4*)(XN + (size_t)(r0 + r) * DD))[c4] = v;
        }
    }
}

__global__ __launch_bounds__(384) void dgc_fused(const float* __restrict__ XT,
                                                 const float* __restrict__ XN,
                                                 const int* __restrict__ gt,
                                                 float* __restrict__ out) {
    __shared__ float  xs[DD];         // normalized row n
    __shared__ float4 pacc[4][96];    // k-chunk partial dots (float4 over j)
    __shared__ float  srow[NN];       // scaled similarity row
    __shared__ float  vsort[NN];
    __shared__ int    sidx[NN];
    __shared__ int    hist[NBUCK];
    __shared__ int    pre[NBUCK + 1];
    __shared__ int    wcnt[6][6];     // [wave][g] ballot counts
    __shared__ int    gcum[6];
    __shared__ float  redd[6], redi[6];

    const int n    = blockIdx.x;
    const int t    = threadIdx.x;
    const int lane = t & 63;
    const int wave = t >> 6;

    if (t < DD / 4) ((float4*)xs)[t] = ((const float4*)(XN + (size_t)n * DD))[t];
    if (t < NBUCK) hist[t] = 0;
    __syncthreads();

    // ---- gram, split-K float4: j4 = t%96 (4 j's), kc = t/96 (64 k's) ----
    {
        const int j4 = t % 96;
        const int kc = t / 96;
        const float4* XT4 = (const float4*)XT;
        float4 a = {0.0f, 0.0f, 0.0f, 0.0f};
        const int k0 = kc * 64;
        #pragma unroll 8
        for (int m = 0; m < 64; ++m) {
            const int k = k0 + m;
            float4 b = XT4[(size_t)k * 96 + j4];   // 16B/lane, coalesced
            float  s = xs[k];                      // LDS broadcast
            a.x = fmaf(s, b.x, a.x); a.y = fmaf(s, b.y, a.y);
            a.z = fmaf(s, b.z, a.z); a.w = fmaf(s, b.w, a.w);
        }
        pacc[kc][j4] = a;
    }
    __syncthreads();
    {   // reduce 4 k-chunks; flat float view: [kc*384 + j]
        const float* pf = (const float*)pacc;
        float dot = pf[t] + pf[384 + t] + pf[768 + t] + pf[1152 + t];
        srow[t] = fmaf(dot, HSCALE, HSCALE);
    }
    __syncthreads();

    const float vraw = srow[t];
    const float sn   = srow[n];       // LDS broadcast

    // ---- counting sort, phase 1: bucket insert ----
    int b = (int)(vraw * BSCALE);
    b = b < 0 ? 0 : (b > NBUCK - 1 ? NBUCK - 1 : b);
    const int slot = atomicAdd(&hist[b], 1);

    // ---- idcg histogram via ballot ----
    const bool validc = (t < MM);
    int gi = 0;
    if (validc) {
        const int gd = gt[t + (t >= n ? 1 : 0)] - gt[n];
        gi = gd < 0 ? -gd : gd;       // 0..5
    }
    #pragma unroll
    for (int g = 0; g < 6; ++g) {
        unsigned long long m = __ballot(validc && (gi == g));
        if (lane == g) wcnt[wave][g] = __popcll(m);
    }
    __syncthreads();

    // ---- phase 2: wave 0 exclusive-scans hist -> pre[0..256]; t==0 gcum ----
    if (wave == 0) {
        const int s0 = hist[lane * 4 + 0], s1 = hist[lane * 4 + 1];
        const int s2 = hist[lane * 4 + 2], s3 = hist[lane * 4 + 3];
        const int sum = s0 + s1 + s2 + s3;
        int inc = sum;
        #pragma unroll
        for (int off = 1; off < 64; off <<= 1) {
            int u = __shfl_up(inc, off, 64);
            if (lane >= off) inc += u;
        }
        const int base = inc - sum;
        pre[lane * 4 + 0] = base;
        pre[lane * 4 + 1] = base + s0;
        pre[lane * 4 + 2] = base + s0 + s1;
        pre[lane * 4 + 3] = base + s0 + s1 + s2;
        if (lane == 63) pre[NBUCK] = inc;        // = 384
    }
    if (t == 0) {
        int s = 0;
        #pragma unroll
        for (int g = 0; g < 6; ++g) {
            s += wcnt[0][g] + wcnt[1][g] + wcnt[2][g]
               + wcnt[3][g] + wcnt[4][g] + wcnt[5][g];
            gcum[g] = s;
        }
    }
    __syncthreads();

    // ---- phase 3: scatter into bucket-sorted order ----
    {
        const int pos = pre[b] + slot;
        vsort[pos] = vraw;
        sidx[pos]  = t;
    }
    __syncthreads();

    // ---- phase 4: thread = sorted position t; soft window only ----
    const float ri    = vsort[t];
    const int   iorig = sidx[t];

    int Blo = (int)((ri - WWIN) * BSCALE);
    int Bhi = (int)((ri + WWIN) * BSCALE);
    Blo = Blo < 0 ? 0 : (Blo > NBUCK - 1 ? NBUCK - 1 : Blo);
    Bhi = Bhi < 0 ? 0 : (Bhi > NBUCK - 1 ? NBUCK - 1 : Bhi);
    const int lo = pre[Blo];        // below: term ~ 0
    const int hi = pre[Bhi + 1];    // at/above: term == 1.0 in fp32 (d >= 24)

    float p0 = 0.0f, p1 = 0.0f;
    int q = lo;
    for (; q + 2 <= hi; q += 2) {
        p0 += __builtin_amdgcn_rcpf(1.0f + __builtin_amdgcn_exp2f(ri - vsort[q]));
        p1 += __builtin_amdgcn_rcpf(1.0f + __builtin_amdgcn_exp2f(ri - vsort[q + 1]));
    }
    if (q < hi)
        p0 += __builtin_amdgcn_rcpf(1.0f + __builtin_amdgcn_exp2f(ri - vsort[q]));
    float sum_all = (float)(NN - hi) + p0 + p1;

    // diagonal (c == n) correction, bucket-consistent with the window
    int bn = (int)(sn * BSCALE);
    bn = bn < 0 ? 0 : (bn > NBUCK - 1 ? NBUCK - 1 : bn);
    float cd = 0.0f;
    if (bn > Bhi)       cd = 1.0f;
    else if (bn >= Blo) cd = __builtin_amdgcn_rcpf(1.0f + __builtin_amdgcn_exp2f(ri - sn));
    // self term (sigma(0)=0.5) always in-window: ind = 1 + sum - 0.5 - cd
    const float ind = 0.5f + sum_all - cd;

    // ---- idcg at sorted-rel position p = t ----
    float idcg_i = 0.0f;
    if (validc) {
        const int p = t;
        const int g = (p >= gcum[0]) + (p >= gcum[1]) + (p >= gcum[2])
                    + (p >= gcum[3]) + (p >= gcum[4]);   // gcum[5]==383 > p
        idcg_i = (float)((1 << (10 - g)) - 1) / __builtin_amdgcn_logf((float)(p + 2));
    }

    // ---- dcg for this sorted position ----
    float dcg_i = 0.0f;
    if (iorig != n) {               // permutation covers all 383 real cols
        const int gd = gt[iorig] - gt[n];
        const int gg = gd < 0 ? -gd : gd;
        dcg_i = (float)((1 << (10 - gg)) - 1) / __builtin_amdgcn_logf(ind + 1.0f);
    }

    #pragma unroll
    for (int off = 32; off > 0; off >>= 1) {
        dcg_i  += __shfl_down(dcg_i,  off, 64);
        idcg_i += __shfl_down(idcg_i, off, 64);
    }
    if (lane == 0) { redd[wave] = dcg_i; redi[wave] = idcg_i; }
    __syncthreads();
    if (t == 0) {
        float d = 0.0f, id = 0.0f;
        #pragma unroll
        for (int w = 0; w < 6; ++w) { d += redd[w]; id += redi[w]; }
        atomicAdd(out, -(d / id) * (1.0f / (float)NN));   // relaxed scope
    }
}

extern "C" void kernel_launch(void* const* d_in, const int* in_sizes, int n_in,
                              void* d_out, int out_size, void* d_ws, size_t ws_size,
                              hipStream_t stream) {
    const float* ranking = (const float*)d_in[0];
    const int*   gt      = (const int*)d_in[1];
    float*       out     = (float*)d_out;

    float* XT = (float*)d_ws;                  // 256*384
    float* XN = XT + (size_t)DD * NN;          // 384*256

    dgc_normT<<<24, 256, 0, stream>>>(ranking, XT, XN, out);
    dgc_fused<<<NN, 384, 0, stream>>>(XT, XN, gt, out);
}

// Round 11
// 73.236 us; speedup vs baseline: 1.2078x; 1.0118x over previous
//
#include <hip/hip_runtime.h>

// DGCLoss: 1 - mean NDCG. N=384 rows, D=256 feats, M=383 off-diag cols.
//
// Round 11: (a) WWIN 16->12 (soft terms -25%; worst-row ind error ~1.2e-3,
// loss error ~5e-4 vs 3.6e-3 threshold); (b) final same-address atomicAdd
// (384 blocks -> 1 cache line, cross-XCD serialized) replaced by plain
// ndcg[n] store + 1-block reduce kernel.
//   dgc_normT : 24 blocks: norms -> XT + XN.
//   dgc_fused : block n: split-K float4 gram -> srow, counting sort,
//               soft-window sigmoid, ballot idcg, store ndcg[n].
//   dgc_final : 1 block: out = 1 - mean(ndcg).

#define NN 384
#define DD 256
#define MM 383
// exp(-d*1000) == exp2(s_i - s_j) with s = ((cos+1)*0.5) * 1000*log2(e)
#define HSCALE 721.3475204444817f   // 0.5 * 1000 * log2(e)
#define NBUCK  256
#define BSCALE 0.1767955801104972f  // 256 / 1448  (values in [0, 1442.7])
#define WWIN   12.0f                // soft-window half-width in s-units

__global__ __launch_bounds__(256) void dgc_normT(const float* __restrict__ x,
                                                 float* __restrict__ XT,
                                                 float* __restrict__ XN) {
    __shared__ float xs[16][260];   // +4 pad: conflict-free
    __shared__ float invn[16];

    const int t  = threadIdx.x;
    const int r0 = blockIdx.x * 16;

    #pragma unroll
    for (int i = 0; i < 4; ++i) {
        int f = t + i * 256;            // float4 unit 0..1023
        int r = f >> 6, c4 = f & 63;
        float4 v = ((const float4*)(x + (size_t)(r0 + r) * DD))[c4];
        xs[r][c4 * 4 + 0] = v.x; xs[r][c4 * 4 + 1] = v.y;
        xs[r][c4 * 4 + 2] = v.z; xs[r][c4 * 4 + 3] = v.w;
    }
    __syncthreads();

    {   // row norms: 16 threads per row
        const int r = t >> 4, sub = t & 15;
        float s = 0.0f;
        #pragma unroll
        for (int m = 0; m < 16; ++m) {
            float v = xs[r][sub * 16 + m];
            s = fmaf(v, v, s);
        }
        #pragma unroll
        for (int off = 8; off > 0; off >>= 1) s += __shfl_xor(s, off, 64);
        if (sub == 0) invn[r] = __builtin_amdgcn_rsqf(fmaxf(s, 1e-16f));
    }
    __syncthreads();

    {   // normalized transpose XT[k][r0+r]
        const int r  = t & 15;
        const int kk = t >> 4;
        const float inv = invn[r];
        #pragma unroll
        for (int i = 0; i < 16; ++i) {
            int k = i * 16 + kk;
            XT[(size_t)k * NN + r0 + r] = xs[r][k] * inv;
        }
    }
    {   // normalized row-major XN (coalesced)
        #pragma unroll
        for (int i = 0; i < 4; ++i) {
            int f = t + i * 256;
            int r = f >> 6, c4 = f & 63;
            const float inv = invn[r];
            float4 v;
            v.x = xs[r][c4 * 4 + 0] * inv; v.y = xs[r][c4 * 4 + 1] * inv;
            v.z = xs[r][c4 * 4 + 2] * inv; v.w = xs[r][c4 * 4 + 3] * inv;
            ((float4*)(XN + (size_t)(r0 + r) * DD))[c4] = v;
        }
    }
}

__global__ __launch_bounds__(384) void dgc_fused(const float* __restrict__ XT,
                                                 const float* __restrict__ XN,
                                                 const int* __restrict__ gt,
                                                 float* __restrict__ ndcg) {
    __shared__ float  xs[DD];         // normalized row n
    __shared__ float4 pacc[4][96];    // k-chunk partial dots (float4 over j)
    __shared__ float  srow[NN];       // scaled similarity row
    __shared__ float  vsort[NN];
    __shared__ int    sidx[NN];
    __shared__ int    hist[NBUCK];
    __shared__ int    pre[NBUCK + 1];
    __shared__ int    wcnt[6][6];     // [wave][g] ballot counts
    __shared__ int    gcum[6];
    __shared__ float  redd[6], redi[6];

    const int n    = blockIdx.x;
    const int t    = threadIdx.x;
    const int lane = t & 63;
    const int wave = t >> 6;

    if (t < DD / 4) ((float4*)xs)[t] = ((const float4*)(XN + (size_t)n * DD))[t];
    if (t < NBUCK) hist[t] = 0;
    __syncthreads();

    // ---- gram, split-K float4: j4 = t%96 (4 j's), kc = t/96 (64 k's) ----
    {
        const int j4 = t % 96;
        const int kc = t / 96;
        const float4* XT4 = (const float4*)XT;
        float4 a = {0.0f, 0.0f, 0.0f, 0.0f};
        const int k0 = kc * 64;
        #pragma unroll 8
        for (int m = 0; m < 64; ++m) {
            const int k = k0 + m;
            float4 b = XT4[(size_t)k * 96 + j4];   // 16B/lane, coalesced
            float  s = xs[k];                      // LDS broadcast
            a.x = fmaf(s, b.x, a.x); a.y = fmaf(s, b.y, a.y);
            a.z = fmaf(s, b.z, a.z); a.w = fmaf(s, b.w, a.w);
        }
        pacc[kc][j4] = a;
    }
    __syncthreads();
    {   // reduce 4 k-chunks; flat float view: [kc*384 + j]
        const float* pf = (const float*)pacc;
        float dot = pf[t] + pf[384 + t] + pf[768 + t] + pf[1152 + t];
        srow[t] = fmaf(dot, HSCALE, HSCALE);
    }
    __syncthreads();

    const float vraw = srow[t];
    const float sn   = srow[n];       // LDS broadcast

    // ---- counting sort, phase 1: bucket insert ----
    int b = (int)(vraw * BSCALE);
    b = b < 0 ? 0 : (b > NBUCK - 1 ? NBUCK - 1 : b);
    const int slot = atomicAdd(&hist[b], 1);

    // ---- idcg histogram via ballot ----
    const bool validc = (t < MM);
    int gi = 0;
    if (validc) {
        const int gd = gt[t + (t >= n ? 1 : 0)] - gt[n];
        gi = gd < 0 ? -gd : gd;       // 0..5
    }
    #pragma unroll
    for (int g = 0; g < 6; ++g) {
        unsigned long long m = __ballot(validc && (gi == g));
        if (lane == g) wcnt[wave][g] = __popcll(m);
    }
    __syncthreads();

    // ---- phase 2: wave 0 exclusive-scans hist -> pre[0..256]; t==0 gcum ----
    if (wave == 0) {
        const int s0 = hist[lane * 4 + 0], s1 = hist[lane * 4 + 1];
        const int s2 = hist[lane * 4 + 2], s3 = hist[lane * 4 + 3];
        const int sum = s0 + s1 + s2 + s3;
        int inc = sum;
        #pragma unroll
        for (int off = 1; off < 64; off <<= 1) {
            int u = __shfl_up(inc, off, 64);
            if (lane >= off) inc += u;
        }
        const int base = inc - sum;
        pre[lane * 4 + 0] = base;
        pre[lane * 4 + 1] = base + s0;
        pre[lane * 4 + 2] = base + s0 + s1;
        pre[lane * 4 + 3] = base + s0 + s1 + s2;
        if (lane == 63) pre[NBUCK] = inc;        // = 384
    }
    if (t == 0) {
        int s = 0;
        #pragma unroll
        for (int g = 0; g < 6; ++g) {
            s += wcnt[0][g] + wcnt[1][g] + wcnt[2][g]
               + wcnt[3][g] + wcnt[4][g] + wcnt[5][g];
            gcum[g] = s;
        }
    }
    __syncthreads();

    // ---- phase 3: scatter into bucket-sorted order ----
    {
        const int pos = pre[b] + slot;
        vsort[pos] = vraw;
        sidx[pos]  = t;
    }
    __syncthreads();

    // ---- phase 4: thread = sorted position t; soft window only ----
    const float ri    = vsort[t];
    const int   iorig = sidx[t];

    int Blo = (int)((ri - WWIN) * BSCALE);
    int Bhi = (int)((ri + WWIN) * BSCALE);
    Blo = Blo < 0 ? 0 : (Blo > NBUCK - 1 ? NBUCK - 1 : Blo);
    Bhi = Bhi < 0 ? 0 : (Bhi > NBUCK - 1 ? NBUCK - 1 : Bhi);
    const int lo = pre[Blo];        // below: term ~ 0
    const int hi = pre[Bhi + 1];    // at/above: term ~ 1

    float p0 = 0.0f, p1 = 0.0f;
    int q = lo;
    for (; q + 2 <= hi; q += 2) {
        p0 += __builtin_amdgcn_rcpf(1.0f + __builtin_amdgcn_exp2f(ri - vsort[q]));
        p1 += __builtin_amdgcn_rcpf(1.0f + __builtin_amdgcn_exp2f(ri - vsort[q + 1]));
    }
    if (q < hi)
        p0 += __builtin_amdgcn_rcpf(1.0f + __builtin_amdgcn_exp2f(ri - vsort[q]));
    float sum_all = (float)(NN - hi) + p0 + p1;

    // diagonal (c == n) correction, bucket-consistent with the window
    int bn = (int)(sn * BSCALE);
    bn = bn < 0 ? 0 : (bn > NBUCK - 1 ? NBUCK - 1 : bn);
    float cd = 0.0f;
    if (bn > Bhi)       cd = 1.0f;
    else if (bn >= Blo) cd = __builtin_amdgcn_rcpf(1.0f + __builtin_amdgcn_exp2f(ri - sn));
    // self term (sigma(0)=0.5) always in-window: ind = 1 + sum - 0.5 - cd
    const float ind = 0.5f + sum_all - cd;

    // ---- idcg at sorted-rel position p = t ----
    float idcg_i = 0.0f;
    if (validc) {
        const int p = t;
        const int g = (p >= gcum[0]) + (p >= gcum[1]) + (p >= gcum[2])
                    + (p >= gcum[3]) + (p >= gcum[4]);   // gcum[5]==383 > p
        idcg_i = (float)((1 << (10 - g)) - 1) / __builtin_amdgcn_logf((float)(p + 2));
    }

    // ---- dcg for this sorted position ----
    float dcg_i = 0.0f;
    if (iorig != n) {               // permutation covers all 383 real cols
        const int gd = gt[iorig] - gt[n];
        const int gg = gd < 0 ? -gd : gd;
        dcg_i = (float)((1 << (10 - gg)) - 1) / __builtin_amdgcn_logf(ind + 1.0f);
    }

    #pragma unroll
    for (int off = 32; off > 0; off >>= 1) {
        dcg_i  += __shfl_down(dcg_i,  off, 64);
        idcg_i += __shfl_down(idcg_i, off, 64);
    }
    if (lane == 0) { redd[wave] = dcg_i; redi[wave] = idcg_i; }
    __syncthreads();
    if (t == 0) {
        float d = 0.0f, id = 0.0f;
        #pragma unroll
        for (int w = 0; w < 6; ++w) { d += redd[w]; id += redi[w]; }
        ndcg[n] = d / id;             // plain store; no cross-XCD atomic
    }
}

__global__ __launch_bounds__(384) void dgc_final(const float* __restrict__ ndcg,
                                                 float* __restrict__ out) {
    __shared__ float red[6];
    const int t    = threadIdx.x;
    const int lane = t & 63;
    const int wave = t >> 6;
    float nd = ndcg[t];
    #pragma unroll
    for (int off = 32; off > 0; off >>= 1) nd += __shfl_down(nd, off, 64);
    if (lane == 0) red[wave] = nd;
    __syncthreads();
    if (t == 0) {
        float s = 0.0f;
        for (int w = 0; w < 6; ++w) s += red[w];
        out[0] = 1.0f - s / (float)NN;
    }
}

extern "C" void kernel_launch(void* const* d_in, const int* in_sizes, int n_in,
                              void* d_out, int out_size, void* d_ws, size_t ws_size,
                              hipStream_t stream) {
    const float* ranking = (const float*)d_in[0];
    const int*   gt      = (const int*)d_in[1];
    float*       out     = (float*)d_out;

    float* XT   = (float*)d_ws;                  // 256*384
    float* XN   = XT + (size_t)DD * NN;          // 384*256
    float* ndcg = XN + (size_t)NN * DD;          // 384

    dgc_normT<<<24, 256, 0, stream>>>(ranking, XT, XN);
    dgc_fused<<<NN, 384, 0, stream>>>(XT, XN, gt, ndcg);
    dgc_final<<<1, 384, 0, stream>>>(ndcg, out);
}

// Round 12
// 70.098 us; speedup vs baseline: 1.2618x; 1.0448x over previous
//
#include <hip/hip_runtime.h>

// DGCLoss: 1 - mean NDCG. N=384 rows, D=256 feats, M=383 off-diag cols.
//
// Round 12: (a) 2 rows/block -> gram L2 traffic halved (151->75 MB), single
// block round; (b) idcg depends only on gt[n] -> 6-entry table precomputed
// in normT block 24, fused drops all idcg machinery; (c) WWIN 12->6 (tail
// errors cancel to first order; loss error ~1e-5 vs 3.6e-3 threshold).
//   dgc_normT : 25 blocks: 0-23 transpose+normalize -> XT/XN; 24 idcg_tab.
//   dgc_fused : block = rows (2b, 2b+1): shared XT stream gram -> 2 srows,
//               2 counting sorts, soft-window sigmoid, ndcg[n] stores.
//   dgc_final : 1 block: out = 1 - mean(ndcg).

#define NN 384
#define DD 256
#define MM 383
// exp(-d*1000) == exp2(s_i - s_j) with s = ((cos+1)*0.5) * 1000*log2(e)
#define HSCALE 721.3475204444817f   // 0.5 * 1000 * log2(e)
#define NBUCK  256
#define BSCALE 0.1767955801104972f  // 256 / 1448  (values in [0, 1442.7])
#define WWIN   6.0f                 // soft-window half-width in s-units

__global__ __launch_bounds__(256) void dgc_normT(const float* __restrict__ x,
                                                 const int* __restrict__ gt,
                                                 float* __restrict__ XT,
                                                 float* __restrict__ XN,
                                                 float* __restrict__ idcg_tab) {
    const int t = threadIdx.x;

    if (blockIdx.x == 24) {
        // ---- idcg table: idcg for a row with gt[n] == gv, gv = 0..5 ----
        __shared__ int   cnt[6];
        __shared__ int   cum[6][6];
        __shared__ float wred[4][6];
        const int lane = t & 63;
        const int wave = t >> 6;

        if (t < 6) cnt[t] = 0;
        __syncthreads();
        atomicAdd(&cnt[gt[t]], 1);                    // t: 0..255
        if (t + 256 < NN) atomicAdd(&cnt[gt[t + 256]], 1);
        __syncthreads();
        if (t < 6) {                                  // t = gv
            int h[6];
            #pragma unroll
            for (int g = 0; g < 6; ++g) h[g] = 0;
            #pragma unroll
            for (int v = 0; v < 6; ++v) {
                int d = v - t; d = d < 0 ? -d : d;
                h[d] += cnt[v];
            }
            h[0] -= 1;                                // remove self term
            int s = 0;
            #pragma unroll
            for (int g = 0; g < 6; ++g) { s += h[g]; cum[t][g] = s; }
        }
        __syncthreads();

        float acc[6] = {0.f, 0.f, 0.f, 0.f, 0.f, 0.f};
        for (int p = t; p < MM; p += 256) {
            const float invl = 1.0f / __builtin_amdgcn_logf((float)(p + 2));
            #pragma unroll
            for (int gv = 0; gv < 6; ++gv) {
                const int g = (p >= cum[gv][0]) + (p >= cum[gv][1])
                            + (p >= cum[gv][2]) + (p >= cum[gv][3])
                            + (p >= cum[gv][4]);
                acc[gv] += (float)((1 << (10 - g)) - 1) * invl;
            }
        }
        for (int off = 32; off > 0; off >>= 1) {
            #pragma unroll
            for (int gv = 0; gv < 6; ++gv) acc[gv] += __shfl_down(acc[gv], off, 64);
        }
        if (lane == 0) {
            #pragma unroll
            for (int gv = 0; gv < 6; ++gv) wred[wave][gv] = acc[gv];
        }
        __syncthreads();
        if (t < 6) idcg_tab[t] = wred[0][t] + wred[1][t] + wred[2][t] + wred[3][t];
        return;
    }

    // ---- transpose + normalize (blocks 0..23) ----
    __shared__ float xs[16][260];   // +4 pad: conflict-free
    __shared__ float invn[16];
    const int r0 = blockIdx.x * 16;

    #pragma unroll
    for (int i = 0; i < 4; ++i) {
        int f = t + i * 256;            // float4 unit 0..1023
        int r = f >> 6, c4 = f & 63;
        float4 v = ((const float4*)(x + (size_t)(r0 + r) * DD))[c4];
        xs[r][c4 * 4 + 0] = v.x; xs[r][c4 * 4 + 1] = v.y;
        xs[r][c4 * 4 + 2] = v.z; xs[r][c4 * 4 + 3] = v.w;
    }
    __syncthreads();

    {   // row norms: 16 threads per row
        const int r = t >> 4, sub = t & 15;
        float s = 0.0f;
        #pragma unroll
        for (int m = 0; m < 16; ++m) {
            float v = xs[r][sub * 16 + m];
            s = fmaf(v, v, s);
        }
        #pragma unroll
        for (int off = 8; off > 0; off >>= 1) s += __shfl_xor(s, off, 64);
        if (sub == 0) invn[r] = __builtin_amdgcn_rsqf(fmaxf(s, 1e-16f));
    }
    __syncthreads();

    {   // normalized transpose XT[k][r0+r]
        const int r  = t & 15;
        const int kk = t >> 4;
        const float inv = invn[r];
        #pragma unroll
        for (int i = 0; i < 16; ++i) {
            int k = i * 16 + kk;
            XT[(size_t)k * NN + r0 + r] = xs[r][k] * inv;
        }
    }
    {   // normalized row-major XN (coalesced)
        #pragma unroll
        for (int i = 0; i < 4; ++i) {
            int f = t + i * 256;
            int r = f >> 6, c4 = f & 63;
            const float inv = invn[r];
            float4 v;
            v.x = xs[r][c4 * 4 + 0] * inv; v.y = xs[r][c4 * 4 + 1] * inv;
            v.z = xs[r][c4 * 4 + 2] * inv; v.w = xs[r][c4 * 4 + 3] * inv;
            ((float4*)(XN + (size_t)(r0 + r) * DD))[c4] = v;
        }
    }
}

__global__ __launch_bounds__(768) void dgc_fused(const float* __restrict__ XT,
                                                 const float* __restrict__ XN,
                                                 const int* __restrict__ gt,
                                                 const float* __restrict__ idcg_tab,
                                                 float* __restrict__ ndcg) {
    __shared__ float  xs[2][DD];        // normalized rows n0, n0+1
    __shared__ float4 pacc[2][8][96];   // [row][k-chunk][j4] partial dots (24 KB)
    __shared__ float  srow[2][NN];
    __shared__ float  vsort[2][NN];
    __shared__ int    sidx[2][NN];
    __shared__ int    hist[2][NBUCK];
    __shared__ int    pre[2][NBUCK + 1];
    __shared__ float  redd[12];

    const int n0   = blockIdx.x * 2;
    const int t    = threadIdx.x;
    const int lane = t & 63;
    const int wave = t >> 6;

    if (t < 128)
        ((float4*)xs[t >> 6])[t & 63] =
            ((const float4*)(XN + (size_t)(n0 + (t >> 6)) * DD))[t & 63];
    if (t < 512) ((int*)hist)[t] = 0;
    __syncthreads();

    // ---- gram: j4 = t%96 (4 cols), kc = t/96 (8 chunks of 32 k's).
    //      Each XT float4 loaded ONCE, fma'd into both rows. ----
    {
        const int j4 = t % 96;
        const int kc = t / 96;                 // 0..7
        const float4* XT4 = (const float4*)XT;
        float4 a0 = {0.f, 0.f, 0.f, 0.f};
        float4 a1 = {0.f, 0.f, 0.f, 0.f};
        const int k0 = kc * 32;
        #pragma unroll 8
        for (int m = 0; m < 32; ++m) {
            const int k = k0 + m;
            float4 b = XT4[(size_t)k * 96 + j4];   // coalesced, loaded once
            float s0 = xs[0][k];
            float s1 = xs[1][k];
            a0.x = fmaf(s0, b.x, a0.x); a0.y = fmaf(s0, b.y, a0.y);
            a0.z = fmaf(s0, b.z, a0.z); a0.w = fmaf(s0, b.w, a0.w);
            a1.x = fmaf(s1, b.x, a1.x); a1.y = fmaf(s1, b.y, a1.y);
            a1.z = fmaf(s1, b.z, a1.z); a1.w = fmaf(s1, b.w, a1.w);
        }
        pacc[0][kc][j4] = a0;
        pacc[1][kc][j4] = a1;
    }
    __syncthreads();

    const int r = t / 384;                 // row-half: waves 0-5 -> 0, 6-11 -> 1
    const int u = t - r * 384;             // 0..383

    {   // reduce 8 k-chunks; flat float view per row: [kc*384 + u]
        const float* pf = (const float*)pacc[r];
        float dot = 0.0f;
        #pragma unroll
        for (int c = 0; c < 8; ++c) dot += pf[c * 384 + u];
        srow[r][u] = fmaf(dot, HSCALE, HSCALE);
    }
    __syncthreads();

    // ---- counting sort per row ----
    const float vraw = srow[r][u];
    int b = (int)(vraw * BSCALE);
    b = b < 0 ? 0 : (b > NBUCK - 1 ? NBUCK - 1 : b);
    const int slot = atomicAdd(&hist[r][b], 1);
    __syncthreads();

    if (wave == 0 || wave == 6) {          // one scan wave per row
        const int rr = wave / 6;
        const int s0 = hist[rr][lane * 4 + 0], s1 = hist[rr][lane * 4 + 1];
        const int s2 = hist[rr][lane * 4 + 2], s3 = hist[rr][lane * 4 + 3];
        const int sum = s0 + s1 + s2 + s3;
        int inc = sum;
        #pragma unroll
        for (int off = 1; off < 64; off <<= 1) {
            int uu = __shfl_up(inc, off, 64);
            if (lane >= off) inc += uu;
        }
        const int base = inc - sum;
        pre[rr][lane * 4 + 0] = base;
        pre[rr][lane * 4 + 1] = base + s0;
        pre[rr][lane * 4 + 2] = base + s0 + s1;
        pre[rr][lane * 4 + 3] = base + s0 + s1 + s2;
        if (lane == 63) pre[rr][NBUCK] = inc;    // = 384
    }
    __syncthreads();

    {
        const int pos = pre[r][b] + slot;
        vsort[r][pos] = vraw;
        sidx[r][pos]  = u;
    }
    __syncthreads();

    // ---- soft window at sorted position u of row r ----
    const int   nrow  = n0 + r;
    const float ri    = vsort[r][u];
    const int   iorig = sidx[r][u];
    const float sn    = srow[r][nrow];

    int Blo = (int)((ri - WWIN) * BSCALE);
    int Bhi = (int)((ri + WWIN) * BSCALE);
    Blo = Blo < 0 ? 0 : (Blo > NBUCK - 1 ? NBUCK - 1 : Blo);
    Bhi = Bhi < 0 ? 0 : (Bhi > NBUCK - 1 ? NBUCK - 1 : Bhi);
    const int lo = pre[r][Blo];        // below: term ~ 0
    const int hi = pre[r][Bhi + 1];    // at/above: term ~ 1

    float p0 = 0.0f, p1 = 0.0f;
    int q = lo;
    for (; q + 2 <= hi; q += 2) {
        p0 += __builtin_amdgcn_rcpf(1.0f + __builtin_amdgcn_exp2f(ri - vsort[r][q]));
        p1 += __builtin_amdgcn_rcpf(1.0f + __builtin_amdgcn_exp2f(ri - vsort[r][q + 1]));
    }
    if (q < hi)
        p0 += __builtin_amdgcn_rcpf(1.0f + __builtin_amdgcn_exp2f(ri - vsort[r][q]));
    float sum_all = (float)(NN - hi) + p0 + p1;

    // diagonal (c == nrow) correction, bucket-consistent with the window
    int bn = (int)(sn * BSCALE);
    bn = bn < 0 ? 0 : (bn > NBUCK - 1 ? NBUCK - 1 : bn);
    float cd = 0.0f;
    if (bn > Bhi)       cd = 1.0f;
    else if (bn >= Blo) cd = __builtin_amdgcn_rcpf(1.0f + __builtin_amdgcn_exp2f(ri - sn));
    // self term (sigma(0)=0.5) always in-window: ind = 1 + sum - 0.5 - cd
    const float ind = 0.5f + sum_all - cd;

    // ---- dcg term ----
    float dcg_i = 0.0f;
    if (iorig != nrow) {               // permutation covers all 383 real cols
        const int gd = gt[iorig] - gt[nrow];
        const int gg = gd < 0 ? -gd : gd;
        dcg_i = (float)((1 << (10 - gg)) - 1) / __builtin_amdgcn_logf(ind + 1.0f);
    }

    #pragma unroll
    for (int off = 32; off > 0; off >>= 1) dcg_i += __shfl_down(dcg_i, off, 64);
    if (lane == 0) redd[wave] = dcg_i;
    __syncthreads();
    if (t == 0)
        ndcg[n0] = (redd[0] + redd[1] + redd[2] + redd[3] + redd[4] + redd[5])
                   / idcg_tab[gt[n0]];
    if (t == 384)
        ndcg[n0 + 1] = (redd[6] + redd[7] + redd[8] + redd[9] + redd[10] + redd[11])
                       / idcg_tab[gt[n0 + 1]];
}

__global__ __launch_bounds__(384) void dgc_final(const float* __restrict__ ndcg,
                                                 float* __restrict__ out) {
    __shared__ float red[6];
    const int t    = threadIdx.x;
    const int lane = t & 63;
    const int wave = t >> 6;
    float nd = ndcg[t];
    #pragma unroll
    for (int off = 32; off > 0; off >>= 1) nd += __shfl_down(nd, off, 64);
    if (lane == 0) red[wave] = nd;
    __syncthreads();
    if (t == 0) {
        float s = 0.0f;
        for (int w = 0; w < 6; ++w) s += red[w];
        out[0] = 1.0f - s / (float)NN;
    }
}

extern "C" void kernel_launch(void* const* d_in, const int* in_sizes, int n_in,
                              void* d_out, int out_size, void* d_ws, size_t ws_size,
                              hipStream_t stream) {
    const float* ranking = (const float*)d_in[0];
    const int*   gt      = (const int*)d_in[1];
    float*       out     = (float*)d_out;

    float* XT   = (float*)d_ws;                  // 256*384
    float* XN   = XT + (size_t)DD * NN;          // 384*256
    float* ndcg = XN + (size_t)NN * DD;          // 384
    float* tab  = ndcg + NN;                     // 6 (+pad)

    dgc_normT<<<25, 256, 0, stream>>>(ranking, gt, XT, XN, tab);
    dgc_fused<<<NN / 2, 768, 0, stream>>>(XT, XN, gt, tab, ndcg);
    dgc_final<<<1, 384, 0, stream>>>(ndcg, out);
}